// Round 7
// baseline (336.706 us; speedup 1.0000x reference)
//
#include <hip/hip_runtime.h>
#include <stdint.h>

#define HIDN 128
#define EMBN 32

typedef __attribute__((ext_vector_type(8))) short bf16x8;
typedef __attribute__((ext_vector_type(4))) float f32x4;
typedef unsigned long long u64;

// ---------- helpers ----------
__device__ __forceinline__ unsigned bf16r(float f) {   // fp32 -> bf16 bits, RNE
  unsigned u = __float_as_uint(f);
  return (u + 0x7FFFu + ((u >> 16) & 1u)) >> 16;
}
__device__ __forceinline__ unsigned pack2(float a, float b) {  // a -> low16, b -> high16
  return bf16r(a) | (bf16r(b) << 16);
}
__device__ __forceinline__ float blo(unsigned u) { return __uint_as_float(u << 16); }
__device__ __forceinline__ float bhi(unsigned u) { return __uint_as_float(u & 0xFFFF0000u); }
__device__ __forceinline__ float4 f4fma(float s, float4 a, float4 b) {
  return make_float4(fmaf(s, a.x, b.x), fmaf(s, a.y, b.y), fmaf(s, a.z, b.z), fmaf(s, a.w, b.w));
}
__device__ __forceinline__ float4 f4max0(float4 a) {
  return make_float4(fmaxf(a.x, 0.f), fmaxf(a.y, 0.f), fmaxf(a.z, 0.f), fmaxf(a.w, 0.f));
}

// ---------- prep1: Wq'=W2@Wq, Wk'=W2@Wk, biases, Wvsp/bvs (direct), dhd, wv2s ----------
// items: [0,4096) Wqp; [4096,8192) Wkp; [8192,8320) bqp; [8320,8448) bkp;
//        [8448,8576) Wvsp; [8576,8580) bvs; [8580,8584) dhd+wv2s
__global__ __launch_bounds__(256) void k_prep1(
    const float* __restrict__ W2, const float* __restrict__ b2,
    const float* __restrict__ Wq, const float* __restrict__ Wk, const float* __restrict__ Wv,
    const float* __restrict__ Wq2, const float* __restrict__ Wk2, const float* __restrict__ Wv2,
    float* __restrict__ Wqp, float* __restrict__ Wkp,
    float* __restrict__ bqp, float* __restrict__ bkp,
    float* __restrict__ Wvsp, float* __restrict__ bvs,
    float* __restrict__ dhd, float* __restrict__ wv2s)
{
  const float rs = 0.17677669529663687f;  // 1/sqrt(32)
  int idx = blockIdx.x * 256 + threadIdx.x;
  if (idx < 8192) {
    int q = idx < 4096;
    int t = q ? idx : idx - 4096;
    int i = t >> 7, j = t & 127;
    const float* W = q ? Wq : Wk;
    float a = 0.f;
    for (int l = 0; l < HIDN; l++)
      a = fmaf(W2[i * HIDN + l], W[l * HIDN + j], a);
    (q ? Wqp : Wkp)[t] = a;
  } else if (idx < 8448) {
    int q = idx < 8320;
    int j = (q ? idx - 8192 : idx - 8320);
    const float* W = q ? Wq : Wk;
    float a = 0.f;
    for (int l = 0; l < HIDN; l++)
      a = fmaf(b2[l], W[l * HIDN + j], a);
    (q ? bqp : bkp)[j] = a;
  } else if (idx < 8576) {
    int t = idx - 8448;             // Wvsp[i*4+h] = sum_l W2[i][l] * sum_dh Wv[l][h*32+dh]
    int i = t >> 2, h = t & 3;
    float a = 0.f;
    for (int l = 0; l < HIDN; l++) {
      float s = 0.f;
      const float* wl = Wv + l * HIDN + h * 32;
      for (int dh = 0; dh < 32; dh++) s += wl[dh];
      a = fmaf(W2[i * HIDN + l], s, a);
    }
    Wvsp[t] = a;
  } else if (idx < 8580) {
    int h = idx - 8576;
    float a = 0.f;
    for (int l = 0; l < HIDN; l++) {
      float s = 0.f;
      const float* wl = Wv + l * HIDN + h * 32;
      for (int dh = 0; dh < 32; dh++) s += wl[dh];
      a = fmaf(b2[l], s, a);
    }
    bvs[h] = a;
  } else if (idx < 8584) {
    int h = idx - 8580;
    float d = 0.f, wsum = 0.f;
    for (int dh = 0; dh < 32; dh++) {
      d = fmaf(Wq2[h * 32 + dh], Wk2[h * 32 + dh], d);
      wsum += Wv2[h * 32 + dh];
    }
    dhd[h]  = d * rs;
    wv2s[h] = wsum;
  }
}

// ---------- prep2: MBpk fragments + c2th (needs Wqp/Wkp) ----------
__global__ __launch_bounds__(256) void k_prep2(
    const float* __restrict__ Wqp, const float* __restrict__ Wkp,
    const float* __restrict__ bqp,
    unsigned short* __restrict__ MBpk,  // [4][2][64][8] bf16 B-frags of M_h (scaled)
    float* __restrict__ c2th)           // [4][32]
{
  const float rs = 0.17677669529663687f;
  int idx = blockIdx.x * 256 + threadIdx.x;
  if (idx < 4096) {
    // B[k=(lane>>4)*8+jj][n=nb*16+(lane&15)], element jj of lane's short8
    int jj = idx & 7, lane = (idx >> 3) & 63, nb = (idx >> 9) & 1, h = idx >> 10;
    int k = (lane >> 4) * 8 + jj;
    int n = nb * 16 + (lane & 15);
    float a = 0.f;
    const float* wq = Wqp + k * HIDN + h * 32;
    const float* wk = Wkp + n * HIDN + h * 32;
    for (int j = 0; j < 32; j++) a = fmaf(wq[j], wk[j], a);
    MBpk[idx] = (unsigned short)bf16r(a * rs);
  } else if (idx < 4224) {
    int t = idx - 4096;
    int h = t >> 5, ip = t & 31;
    float a2 = 0.f;
    for (int j = 0; j < 32; j++)
      a2 = fmaf(bqp[h * 32 + j], Wkp[ip * HIDN + h * 32 + j], a2);
    c2th[h * 32 + ip] = a2 * rs;
  }
}

// ---------- K_front: edge MLP + linked-list pushes for pairs and nodes ----------
__global__ __launch_bounds__(256, 4) void k_front(
    const float* __restrict__ x, const int* __restrict__ eidx, const float* __restrict__ ea,
    const float* __restrict__ W1, const float* __restrict__ b1,
    const float* __restrict__ Wvsp, const float* __restrict__ bvs,
    unsigned* __restrict__ embB, uint2* __restrict__ vsb,
    const int* __restrict__ e2e, int* __restrict__ phead, u64* __restrict__ nxtp,
    const int* __restrict__ n2n, int* __restrict__ nhead, u64* __restrict__ nxtn,
    int E, int EE, int C, int N, int nEdgeB, int nPairB)
{
  int b = blockIdx.x;
  int tid = threadIdx.x;
  if (b < nEdgeB) {
    // ----- edge MLP path -----
    int e = b * 256 + tid;
    if (e >= E) return;
    int si = eidx[e], di = eidx[E + e];
    float xs = x[si], xd = x[di];

    const float4* b4  = (const float4*)b1;
    const float4* w0  = (const float4*)W1;         // row 0 (x_s)
    const float4* w1r = (const float4*)(W1 + 32);  // row 1 (x_d)
    float4 E0, E1, E2, E3, E4, E5, E6, E7;
#define INIT(i) E##i = f4fma(xs, w0[i], f4fma(xd, w1r[i], b4[i]));
    INIT(0) INIT(1) INIT(2) INIT(3) INIT(4) INIT(5) INIT(6) INIT(7)
#undef INIT
    const float4* ea4 = (const float4*)(ea + (size_t)e * 32);
#define ROW(c, wr) { const float4* w_ = (const float4*)(W1 + (size_t)(wr) * 32); \
  E0 = f4fma(c, w_[0], E0); E1 = f4fma(c, w_[1], E1); E2 = f4fma(c, w_[2], E2); E3 = f4fma(c, w_[3], E3); \
  E4 = f4fma(c, w_[4], E4); E5 = f4fma(c, w_[5], E5); E6 = f4fma(c, w_[6], E6); E7 = f4fma(c, w_[7], E7); }
#pragma unroll
    for (int rb = 0; rb < 8; rb++) {
      float4 v = ea4[rb];
      ROW(v.x, 2 + rb * 4 + 0)
      ROW(v.y, 2 + rb * 4 + 1)
      ROW(v.z, 2 + rb * 4 + 2)
      ROW(v.w, 2 + rb * 4 + 3)
    }
#undef ROW
    E0 = f4max0(E0); E1 = f4max0(E1); E2 = f4max0(E2); E3 = f4max0(E3);
    E4 = f4max0(E4); E5 = f4max0(E5); E6 = f4max0(E6); E7 = f4max0(E7);

    uint4 p0, p1, p2, p3;
    p0.x = pack2(E0.x, E0.y); p0.y = pack2(E0.z, E0.w); p0.z = pack2(E1.x, E1.y); p0.w = pack2(E1.z, E1.w);
    p1.x = pack2(E2.x, E2.y); p1.y = pack2(E2.z, E2.w); p1.z = pack2(E3.x, E3.y); p1.w = pack2(E3.z, E3.w);
    p2.x = pack2(E4.x, E4.y); p2.y = pack2(E4.z, E4.w); p2.z = pack2(E5.x, E5.y); p2.w = pack2(E5.z, E5.w);
    p3.x = pack2(E6.x, E6.y); p3.y = pack2(E6.z, E6.w); p3.z = pack2(E7.x, E7.y); p3.w = pack2(E7.z, E7.w);
    uint4* er = (uint4*)(embB + (size_t)e * 16);
    er[0] = p0; er[1] = p1; er[2] = p2; er[3] = p3;

    // vsum[h] = bvs + Wvsp.emb  -> bf16x4 (8 B)
    const float4* wv = (const float4*)Wvsp;
    float4 vs = *(const float4*)bvs;
#define VK(k) { vs = f4fma(E##k.x, wv[4*k+0], vs); vs = f4fma(E##k.y, wv[4*k+1], vs); \
                vs = f4fma(E##k.z, wv[4*k+2], vs); vs = f4fma(E##k.w, wv[4*k+3], vs); }
    VK(0) VK(1) VK(2) VK(3) VK(4) VK(5) VK(6) VK(7)
#undef VK
    vsb[e] = make_uint2(pack2(vs.x, vs.y), pack2(vs.z, vs.w));
  } else if (b < nEdgeB + nPairB) {
    // ----- pair list push: coalesced nxtp store, LLC-resident head exch -----
    int p = (b - nEdgeB) * 256 + tid;
    if (p >= EE) return;
    int es = e2e[p], ed = e2e[EE + p];
    int prev = atomicExch(&phead[ed], p);
    nxtp[p] = ((u64)(unsigned)es << 32) | (unsigned)prev;
  } else {
    // ----- node list push -----
    int c = (b - nEdgeB - nPairB) * 256 + tid;
    if (c >= C) return;
    int ns = n2n[c], nd = n2n[C + c];
    if (nd >= N) return;              // never in practice (randint < N)
    int prev = atomicExch(&nhead[nd], c);
    nxtn[c] = ((u64)(unsigned)ns << 32) | (unsigned)prev;
  }
}

// ---------- K_back: node softmax (chain walk) + MFMA qt-transform + pair softmax ----------
__global__ __launch_bounds__(256, 4) void k_back(
    const unsigned* __restrict__ embB, const unsigned short* __restrict__ MBpk,
    const uint2* __restrict__ vsb, const float* __restrict__ c2th,
    const int* __restrict__ phead, const u64* __restrict__ nxtp,
    const int* __restrict__ nhead, const u64* __restrict__ nxtn,
    const float* __restrict__ x, const float* __restrict__ dhd, const float* __restrict__ wv2s,
    float* __restrict__ out0, float* __restrict__ out1,
    int E, int N, int nNodeB)
{
  __shared__ float qtl[256 * 33];   // [e_local*4+h][33] fp32, pad 33 (bank-clean)
  int b = blockIdx.x;
  int tid = threadIdx.x;
  if (b < nNodeB) {
    // ----- node softmax: one thread per node, two chain walks (exact max) -----
    int nd = b * 256 + tid;
    if (nd >= N) return;
    float xn = x[nd];
    float4 dv = *(const float4*)dhd;
    float d0 = dv.x, d1 = dv.y, d2 = dv.z, d3 = dv.w;

    float amx = -3.4e38f, amn = 3.4e38f;
    int c = nhead[nd];
    while (c != -1) {
      u64 pk = nxtn[c];
      int ns = (int)(pk >> 32);
      c = (int)(unsigned)pk;
      float a = xn * x[ns];
      amx = fmaxf(amx, a); amn = fminf(amn, a);
    }
    float m0 = (d0 > 0.f) ? d0 * amx : d0 * amn;
    float m1 = (d1 > 0.f) ? d1 * amx : d1 * amn;
    float m2 = (d2 > 0.f) ? d2 * amx : d2 * amn;
    float m3 = (d3 > 0.f) ? d3 * amx : d3 * amn;

    float den0 = 0.f, den1 = 0.f, den2 = 0.f, den3 = 0.f;
    float num0 = 0.f, num1 = 0.f, num2 = 0.f, num3 = 0.f;
    c = nhead[nd];
    while (c != -1) {
      u64 pk = nxtn[c];
      int ns = (int)(pk >> 32);
      c = (int)(unsigned)pk;
      float asv = x[ns];
      float a = xn * asv;
      float e0 = __expf(fmaf(a, d0, -m0));
      float e1 = __expf(fmaf(a, d1, -m1));
      float e2 = __expf(fmaf(a, d2, -m2));
      float e3 = __expf(fmaf(a, d3, -m3));
      den0 += e0; den1 += e1; den2 += e2; den3 += e3;
      num0 = fmaf(e0, asv, num0); num1 = fmaf(e1, asv, num1);
      num2 = fmaf(e2, asv, num2); num3 = fmaf(e3, asv, num3);
    }
    float4 wv = *(const float4*)wv2s;
    float acc = wv.x * num0 / (den0 + 1e-16f) + wv.y * num1 / (den1 + 1e-16f)
              + wv.z * num2 / (den2 + 1e-16f) + wv.w * num3 / (den3 + 1e-16f);
    out0[nd] = acc * 0.0078125f;   // 1/128
  } else {
    // ----- pair path: MFMA qt into LDS, then chain-walk softmax per (e,h) -----
    int pb = b - nNodeB;
    int wave = tid >> 6, lane = tid & 63;
    int e0 = pb * 64;
    int we0 = e0 + wave * 16;

    // A fragment: A[m = lane&15][k = (lane>>4)*8 + j] = emb[we0 + m][k]
    union { uint4 u; bf16x8 bv; } af;
    af.u = *((const uint4*)(embB + ((size_t)(we0 + (lane & 15)) << 4)) + (lane >> 4));

#pragma unroll
    for (int h = 0; h < 4; h++) {
#pragma unroll
      for (int nb = 0; nb < 2; nb++) {
        union { uint4 u; bf16x8 bv; } bf;
        bf.u = *(const uint4*)(MBpk + (((h * 2 + nb) * 64 + lane) << 3));
        int col = nb * 16 + (lane & 15);
        float c2v = c2th[h * 32 + col];            // fold c2.emb_k into D (exact)
        f32x4 acc = {c2v, c2v, c2v, c2v};
        acc = __builtin_amdgcn_mfma_f32_16x16x32_bf16(af.bv, bf.bv, acc, 0, 0, 0);
        int rowb = wave * 16 + (lane >> 4) * 4;
#pragma unroll
        for (int r = 0; r < 4; r++)
          qtl[((rowb + r) * 4 + h) * 33 + col] = acc[r];
      }
    }
    __syncthreads();

    int e = e0 + (tid >> 2);
    if (e >= E) return;
    int h = tid & 3;
    const float* q = qtl + tid * 33;   // (e_local*4 + h) == tid

    float den = 0.f, num = 0.f;
    int p = phead[e];
    while (p != -1) {
      u64 pk = nxtp[p];
      int es = (int)(pk >> 32);
      p = (int)(unsigned)pk;
      const uint4* ep = (const uint4*)(embB + ((size_t)es << 4));
      uint4 u0 = ep[0], u1 = ep[1], u2 = ep[2], u3 = ep[3];
      uint2 vu = vsb[es];
      unsigned vh = (h & 2) ? vu.y : vu.x;
      float vsv = (h & 1) ? bhi(vh) : blo(vh);
      float dot = 0.f;
#define DOT8(uu, base) \
      dot = fmaf(q[base + 0], blo(uu.x), dot); dot = fmaf(q[base + 1], bhi(uu.x), dot); \
      dot = fmaf(q[base + 2], blo(uu.y), dot); dot = fmaf(q[base + 3], bhi(uu.y), dot); \
      dot = fmaf(q[base + 4], blo(uu.z), dot); dot = fmaf(q[base + 5], bhi(uu.z), dot); \
      dot = fmaf(q[base + 6], blo(uu.w), dot); dot = fmaf(q[base + 7], bhi(uu.w), dot);
      DOT8(u0, 0) DOT8(u1, 8) DOT8(u2, 16) DOT8(u3, 24)
#undef DOT8
      float ex = __expf(dot);
      den += ex;
      num = fmaf(ex, vsv, num);
    }
    float r = num / (den + 1e-16f);
    r += __shfl_xor(r, 1);
    r += __shfl_xor(r, 2);
    if (h == 0) out1[e] = r * 0.0078125f;   // 1/128
  }
}

extern "C" void kernel_launch(void* const* d_in, const int* in_sizes, int n_in,
                              void* d_out, int out_size, void* d_ws, size_t ws_size,
                              hipStream_t stream)
{
  const float* x   = (const float*)d_in[0];
  const int*   eidx= (const int*)d_in[1];
  const float* ea  = (const float*)d_in[2];
  const int*   e2e = (const int*)d_in[3];
  const int*   n2n = (const int*)d_in[4];
  const float* W1  = (const float*)d_in[5];
  const float* b1  = (const float*)d_in[6];
  const float* W2  = (const float*)d_in[7];
  const float* b2  = (const float*)d_in[8];
  const float* Wq  = (const float*)d_in[9];
  const float* Wk  = (const float*)d_in[10];
  const float* Wv  = (const float*)d_in[11];
  const float* Wq2 = (const float*)d_in[12];
  const float* Wk2 = (const float*)d_in[13];
  const float* Wv2 = (const float*)d_in[14];

  const int N  = in_sizes[0];        // x is [N,1]
  const int E  = in_sizes[1] / 2;
  const int EE = in_sizes[3] / 2;
  const int C  = in_sizes[4] / 2;

  float* out0 = (float*)d_out;       // [N]
  float* out1 = (float*)d_out + N;   // [E]

  char* w = (char*)d_ws;
  size_t off = 0;
  auto alloc = [&](size_t bytes) -> char* {
    char* p = w + off;
    off += (bytes + 255) & ~(size_t)255;
    return p;
  };
  float* Wqp   = (float*)alloc(EMBN * HIDN * 4);
  float* Wkp   = (float*)alloc(EMBN * HIDN * 4);
  float* bqp   = (float*)alloc(HIDN * 4);
  float* bkp   = (float*)alloc(HIDN * 4);
  unsigned short* MBpk = (unsigned short*)alloc(4096 * 2);
  float* c2th  = (float*)alloc(4 * EMBN * 4);
  float* Wvsp  = (float*)alloc(EMBN * 4 * 4);
  float* bvs   = (float*)alloc(16);
  float* dhd   = (float*)alloc(16);
  float* wv2s  = (float*)alloc(16);
  unsigned* embB = (unsigned*)alloc((size_t)E * 16 * 4);     // 25.6 MB (bf16 emb)
  uint2* vsb   = (uint2*)alloc((size_t)E * 8);               // 3.2 MB (bf16 vsum)
  u64*   nxtp  = (u64*)alloc((size_t)EE * 8);                // 6.4 MB (es | next)
  u64*   nxtn  = (u64*)alloc((size_t)C * 8);                 // 6.4 MB (ns | next)
  char* hbase = w + off;                                     // --- 0xFF block (heads) ---
  int*   phead = (int*)alloc((size_t)E * 4);                 // 1.6 MB
  int*   nhead = (int*)alloc((size_t)N * 4);                 // 0.2 MB
  size_t hbytes = (size_t)((w + off) - hbase);

  const int nEdgeB = (E + 255) / 256;
  const int nPairB = (EE + 255) / 256;
  const int nNodeB = (C + 255) / 256;
  const int nNodeSegB  = (N + 255) / 256;
  const int nPairMfmaB = (E + 63) / 64;

  hipMemsetAsync(hbase, 0xFF, hbytes, stream);   // heads = -1 sentinels

  k_prep1<<<34, 256, 0, stream>>>(W2, b2, Wq, Wk, Wv, Wq2, Wk2, Wv2,
                                  Wqp, Wkp, bqp, bkp, Wvsp, bvs, dhd, wv2s);
  k_prep2<<<17, 256, 0, stream>>>(Wqp, Wkp, bqp, MBpk, c2th);
  k_front<<<nEdgeB + nPairB + nNodeB, 256, 0, stream>>>(
      x, eidx, ea, W1, b1, Wvsp, bvs, embB, vsb,
      e2e, phead, nxtp, n2n, nhead, nxtn,
      E, EE, C, N, nEdgeB, nPairB);
  k_back<<<nNodeSegB + nPairMfmaB, 256, 0, stream>>>(
      embB, MBpk, vsb, c2th, phead, nxtp, nhead, nxtn,
      x, dhd, wv2s, out0, out1, E, N, nNodeSegB);
}